// Round 1
// baseline (182.198 us; speedup 1.0000x reference)
//
#include <hip/hip_runtime.h>

#define NSITES 784
#define BS_TOT 16384

// Per-site step:
//  - t points at tensors[n] (32 floats, layout [l][r][p], w(l,r,p)=l*8+r*2+p)
//  - computes both matvecs nl_p[r] = sum_l left[l]*t[l,r,p]  (logits are r=0 comps)
//  - accumulates log-softmax contribution, selects new left by data bit
#define STEP(dval, TP) do {                                                          \
    const float* t_ = (TP);                                                          \
    float p00 = fmaf(left0, t_[0],  fmaf(left1, t_[8],  fmaf(left2, t_[16], left3 * t_[24]))); \
    float p01 = fmaf(left0, t_[1],  fmaf(left1, t_[9],  fmaf(left2, t_[17], left3 * t_[25]))); \
    float p10 = fmaf(left0, t_[2],  fmaf(left1, t_[10], fmaf(left2, t_[18], left3 * t_[26]))); \
    float p11 = fmaf(left0, t_[3],  fmaf(left1, t_[11], fmaf(left2, t_[19], left3 * t_[27]))); \
    float p20 = fmaf(left0, t_[4],  fmaf(left1, t_[12], fmaf(left2, t_[20], left3 * t_[28]))); \
    float p21 = fmaf(left0, t_[5],  fmaf(left1, t_[13], fmaf(left2, t_[21], left3 * t_[29]))); \
    float p30 = fmaf(left0, t_[6],  fmaf(left1, t_[14], fmaf(left2, t_[22], left3 * t_[30]))); \
    float p31 = fmaf(left0, t_[7],  fmaf(left1, t_[15], fmaf(left2, t_[23], left3 * t_[31]))); \
    bool s_ = ((dval) == 1.0f);                                                      \
    float lg0 = p00, lg1 = p01;                                                      \
    float mx_ = fmaxf(lg0, lg1);                                                     \
    float ch_ = s_ ? lg0 : lg1;                                                      \
    acc_nat += (ch_ - mx_);                                                          \
    float ad_ = fabsf(lg0 - lg1);                                                    \
    acc_l2 += __builtin_amdgcn_logf(1.0f + __builtin_amdgcn_exp2f(-ad_ * 1.4426950408889634f)); \
    left0 = s_ ? p00 : p01;                                                          \
    left1 = s_ ? p10 : p11;                                                          \
    left2 = s_ ? p20 : p21;                                                          \
    left3 = s_ ? p30 : p31;                                                          \
} while (0)

__global__ __launch_bounds__(64) void amps_chain_kernel(
    const float* __restrict__ data,      // (BS, N) in {0,1}
    const float* __restrict__ tensors,   // (N, 4, 4, 2)
    float* __restrict__ out)             // (BS,)
{
    int b = blockIdx.x * blockDim.x + threadIdx.x;
    if (b >= BS_TOT) return;

    const float4* row4 = (const float4*)(data + (size_t)b * NSITES); // 196 float4s

    float left0, left1, left2, left3;
    float acc_nat, acc_l2;

    // ---- group 0: sites 0..15 (c), prefetch group 1 (q) ----
    float4 c0 = row4[0], c1 = row4[1], c2 = row4[2], c3 = row4[3];
    float4 q0 = row4[4], q1 = row4[5], q2 = row4[6], q3 = row4[7];

    // site 0 special: left[r] = T[0,0,r,x0]; logp0 = log_softmax(T[0,0,0,:])[x0]
    {
        bool s0 = (c0.x == 1.0f);
        float t0 = tensors[0], t1 = tensors[1];
        float mx = fmaxf(t0, t1);
        float ch = s0 ? t0 : t1;
        acc_nat = (ch - mx);
        float ad = fabsf(t0 - t1);
        acc_l2 = __builtin_amdgcn_logf(1.0f + __builtin_amdgcn_exp2f(-ad * 1.4426950408889634f));
        left0 = s0 ? tensors[0] : tensors[1];
        left1 = s0 ? tensors[2] : tensors[3];
        left2 = s0 ? tensors[4] : tensors[5];
        left3 = s0 ? tensors[6] : tensors[7];
    }
    STEP(c0.y, tensors + 1 * 32);
    STEP(c0.z, tensors + 2 * 32);
    STEP(c0.w, tensors + 3 * 32);
    STEP(c1.x, tensors + 4 * 32);
    STEP(c1.y, tensors + 5 * 32);
    STEP(c1.z, tensors + 6 * 32);
    STEP(c1.w, tensors + 7 * 32);
    STEP(c2.x, tensors + 8 * 32);
    STEP(c2.y, tensors + 9 * 32);
    STEP(c2.z, tensors + 10 * 32);
    STEP(c2.w, tensors + 11 * 32);
    STEP(c3.x, tensors + 12 * 32);
    STEP(c3.y, tensors + 13 * 32);
    STEP(c3.z, tensors + 14 * 32);
    STEP(c3.w, tensors + 15 * 32);
    c0 = q0; c1 = q1; c2 = q2; c3 = q3;

    // ---- groups 1..48: compute group g from c, prefetch group g+1 into q ----
    for (int g = 1; g < 49; ++g) {
        int gp = (g < 48) ? (g + 1) : 48;          // clamp: last prefetch is a harmless re-read
        const float4* rp = row4 + gp * 4;
        q0 = rp[0]; q1 = rp[1]; q2 = rp[2]; q3 = rp[3];

        const float* tb = tensors + (size_t)g * 16 * 32;
        STEP(c0.x, tb + 0 * 32);
        STEP(c0.y, tb + 1 * 32);
        STEP(c0.z, tb + 2 * 32);
        STEP(c0.w, tb + 3 * 32);
        STEP(c1.x, tb + 4 * 32);
        STEP(c1.y, tb + 5 * 32);
        STEP(c1.z, tb + 6 * 32);
        STEP(c1.w, tb + 7 * 32);
        STEP(c2.x, tb + 8 * 32);
        STEP(c2.y, tb + 9 * 32);
        STEP(c2.z, tb + 10 * 32);
        STEP(c2.w, tb + 11 * 32);
        STEP(c3.x, tb + 12 * 32);
        STEP(c3.y, tb + 13 * 32);
        STEP(c3.z, tb + 14 * 32);
        STEP(c3.w, tb + 15 * 32);

        c0 = q0; c1 = q1; c2 = q2; c3 = q3;
    }

    // logp = sum(ch - mx) - ln2 * sum(log2(1 + e))
    out[b] = acc_nat - 0.6931471805599453f * acc_l2;
}

extern "C" void kernel_launch(void* const* d_in, const int* in_sizes, int n_in,
                              void* d_out, int out_size, void* d_ws, size_t ws_size,
                              hipStream_t stream) {
    const float* data    = (const float*)d_in[0];   // (16384, 784) float32
    const float* tensors = (const float*)d_in[1];   // (784, 4, 4, 2) float32
    float* out = (float*)d_out;                     // (16384,) float32

    dim3 grid(BS_TOT / 64), block(64);
    hipLaunchKernelGGL(amps_chain_kernel, grid, block, 0, stream, data, tensors, out);
}

// Round 2
// 79.754 us; speedup vs baseline: 2.2845x; 2.2845x over previous
//
#include <hip/hip_runtime.h>

#define NSITES 784
#define BS_TOT 16384
#define K_SEG 16
#define G_SEG 49   // NSITES / K_SEG

// ---------------- per-site step (verified in round 0, absmax 0) ----------------
// t_ points at tensors[n] (32 floats, layout [l][r][p], flat l*8+r*2+p).
// Computes both matvecs p_r_sel/p_r_other; logits are the r=0 components.
#define STEP(sbit, TP) do {                                                          \
    const float* t_ = (TP);                                                          \
    float p00 = fmaf(left0, t_[0],  fmaf(left1, t_[8],  fmaf(left2, t_[16], left3 * t_[24]))); \
    float p01 = fmaf(left0, t_[1],  fmaf(left1, t_[9],  fmaf(left2, t_[17], left3 * t_[25]))); \
    float p10 = fmaf(left0, t_[2],  fmaf(left1, t_[10], fmaf(left2, t_[18], left3 * t_[26]))); \
    float p11 = fmaf(left0, t_[3],  fmaf(left1, t_[11], fmaf(left2, t_[19], left3 * t_[27]))); \
    float p20 = fmaf(left0, t_[4],  fmaf(left1, t_[12], fmaf(left2, t_[20], left3 * t_[28]))); \
    float p21 = fmaf(left0, t_[5],  fmaf(left1, t_[13], fmaf(left2, t_[21], left3 * t_[29]))); \
    float p30 = fmaf(left0, t_[6],  fmaf(left1, t_[14], fmaf(left2, t_[22], left3 * t_[30]))); \
    float p31 = fmaf(left0, t_[7],  fmaf(left1, t_[15], fmaf(left2, t_[23], left3 * t_[31]))); \
    bool s_ = (sbit);                                                                \
    float lg0 = p00, lg1 = p01;                                                      \
    float mx_ = fmaxf(lg0, lg1);                                                     \
    float ch_ = s_ ? lg0 : lg1;                                                      \
    acc_nat += (ch_ - mx_);                                                          \
    float ad_ = fabsf(lg0 - lg1);                                                    \
    acc_l2 += __builtin_amdgcn_logf(1.0f + __builtin_amdgcn_exp2f(-ad_ * 1.4426950408889634f)); \
    left0 = s_ ? p00 : p01;                                                          \
    left1 = s_ ? p10 : p11;                                                          \
    left2 = s_ ? p20 : p21;                                                          \
    left3 = s_ ? p30 : p31;                                                          \
} while (0)

// ================= kernel 1: pack data bits (coalesced + ballot) =================
// packed[w][b] : bit j of word w = (data[b][w*64+j] == 1.0f)
__global__ __launch_bounds__(256) void pack_kernel(const float* __restrict__ data,
                                                   unsigned long long* __restrict__ packed) {
    int wave = (blockIdx.x * 256 + threadIdx.x) >> 6;   // sample index (one wave per row)
    int lane = threadIdx.x & 63;
    const float* row = data + (size_t)wave * NSITES;
    #pragma unroll
    for (int w = 0; w < 12; ++w) {
        float v = row[w * 64 + lane];
        unsigned long long m = __ballot(v == 1.0f);
        if (lane == 0) packed[(size_t)w * BS_TOT + wave] = m;
    }
    // word 12: only 16 valid bits (sites 768..783)
    float v = (lane < 16) ? row[768 + lane] : 0.0f;
    unsigned long long m = __ballot((lane < 16) && (v == 1.0f));
    if (lane == 0) packed[(size_t)12 * BS_TOT + wave] = m;
}

// ================= kernel 2: per-segment 4x4 matrix products =================
// P_k = M_{kG} * M_{kG+1} * ... * M_{kG+G-1}  (row-vector convention: v_out = v_in * P)
// Pbuf layout: [k][i][j][b]
__global__ __launch_bounds__(256) void phase1_kernel(const float* __restrict__ tensors,
                                                     const unsigned long long* __restrict__ packed,
                                                     float* __restrict__ Pbuf) {
    int b = blockIdx.x * 256 + threadIdx.x;
    int k = blockIdx.y;
    int n = k * G_SEG;

    unsigned long long cur = packed[(size_t)(n >> 6) * BS_TOT + b] >> (n & 63);

    float P[4][4];
    {
        int p = (cur & 1ull) ? 0 : 1;        // x==1 -> phys idx 0
        const float* t = tensors + (size_t)n * 32;
        #pragma unroll
        for (int l = 0; l < 4; ++l)
            #pragma unroll
            for (int j = 0; j < 4; ++j)
                P[l][j] = t[l * 8 + j * 2 + p];
    }
    #pragma unroll 4
    for (int i = 1; i < G_SEG; ++i) {
        ++n; cur >>= 1;
        if ((n & 63) == 0) cur = packed[(size_t)(n >> 6) * BS_TOT + b];
        int p = (cur & 1ull) ? 0 : 1;
        const float* t = tensors + (size_t)n * 32;
        float M[4][4];
        #pragma unroll
        for (int l = 0; l < 4; ++l)
            #pragma unroll
            for (int j = 0; j < 4; ++j)
                M[l][j] = t[l * 8 + j * 2 + p];
        float Q[4][4];
        #pragma unroll
        for (int r = 0; r < 4; ++r)
            #pragma unroll
            for (int j = 0; j < 4; ++j)
                Q[r][j] = fmaf(P[r][0], M[0][j], fmaf(P[r][1], M[1][j],
                          fmaf(P[r][2], M[2][j], P[r][3] * M[3][j])));
        #pragma unroll
        for (int r = 0; r < 4; ++r)
            #pragma unroll
            for (int j = 0; j < 4; ++j)
                P[r][j] = Q[r][j];
    }
    #pragma unroll
    for (int i = 0; i < 4; ++i)
        #pragma unroll
        for (int j = 0; j < 4; ++j)
            Pbuf[((size_t)(k * 4 + i) * 4 + j) * BS_TOT + b] = P[i][j];
}

// ================= kernel 3: serial scan over K segments per sample =================
// prefix[k][r][b] = (e0 * P_0 * ... * P_{k-1})[r]
__global__ __launch_bounds__(256) void phase2_kernel(const float* __restrict__ Pbuf,
                                                     float* __restrict__ prefix) {
    int b = blockIdx.x * 256 + threadIdx.x;
    float l0 = 1.0f, l1 = 0.0f, l2 = 0.0f, l3 = 0.0f;
    for (int k = 0; k < K_SEG; ++k) {
        prefix[((size_t)k * 4 + 0) * BS_TOT + b] = l0;
        prefix[((size_t)k * 4 + 1) * BS_TOT + b] = l1;
        prefix[((size_t)k * 4 + 2) * BS_TOT + b] = l2;
        prefix[((size_t)k * 4 + 3) * BS_TOT + b] = l3;
        if (k < K_SEG - 1) {
            float P[4][4];
            #pragma unroll
            for (int i = 0; i < 4; ++i)
                #pragma unroll
                for (int j = 0; j < 4; ++j)
                    P[i][j] = Pbuf[((size_t)(k * 4 + i) * 4 + j) * BS_TOT + b];
            float n0 = fmaf(l0, P[0][0], fmaf(l1, P[1][0], fmaf(l2, P[2][0], l3 * P[3][0])));
            float n1 = fmaf(l0, P[0][1], fmaf(l1, P[1][1], fmaf(l2, P[2][1], l3 * P[3][1])));
            float n2 = fmaf(l0, P[0][2], fmaf(l1, P[1][2], fmaf(l2, P[2][2], l3 * P[3][2])));
            float n3 = fmaf(l0, P[0][3], fmaf(l1, P[1][3], fmaf(l2, P[2][3], l3 * P[3][3])));
            l0 = n0; l1 = n1; l2 = n2; l3 = n3;
        }
    }
}

// ================= kernel 4: per-segment log-softmax walk =================
// res[k][b] = partial log-prob of sites [kG, (k+1)G)
__global__ __launch_bounds__(256) void phase3_kernel(const float* __restrict__ tensors,
                                                     const unsigned long long* __restrict__ packed,
                                                     const float* __restrict__ prefix,
                                                     float* __restrict__ res) {
    int b = blockIdx.x * 256 + threadIdx.x;
    int k = blockIdx.y;
    int n0 = k * G_SEG;

    float left0 = prefix[((size_t)k * 4 + 0) * BS_TOT + b];
    float left1 = prefix[((size_t)k * 4 + 1) * BS_TOT + b];
    float left2 = prefix[((size_t)k * 4 + 2) * BS_TOT + b];
    float left3 = prefix[((size_t)k * 4 + 3) * BS_TOT + b];
    float acc_nat = 0.0f, acc_l2 = 0.0f;

    unsigned long long cur = packed[(size_t)(n0 >> 6) * BS_TOT + b] >> (n0 & 63);
    #pragma unroll 7
    for (int i = 0; i < G_SEG; ++i) {
        int n = n0 + i;
        if (i > 0) {
            cur >>= 1;
            if ((n & 63) == 0) cur = packed[(size_t)(n >> 6) * BS_TOT + b];
        }
        STEP((cur & 1ull) != 0, tensors + (size_t)n * 32);
    }
    res[(size_t)k * BS_TOT + b] = acc_nat - 0.6931471805599453f * acc_l2;
}

// ================= kernel 5: reduce partials =================
__global__ __launch_bounds__(256) void reduce_kernel(const float* __restrict__ res,
                                                     float* __restrict__ out) {
    int b = blockIdx.x * 256 + threadIdx.x;
    float a = 0.0f;
    #pragma unroll
    for (int k = 0; k < K_SEG; ++k) a += res[(size_t)k * BS_TOT + b];
    out[b] = a;
}

// ================= round-0 fallback (single kernel, known-correct) =================
__global__ __launch_bounds__(64) void amps_chain_kernel(
    const float* __restrict__ data, const float* __restrict__ tensors,
    float* __restrict__ out)
{
    int b = blockIdx.x * blockDim.x + threadIdx.x;
    if (b >= BS_TOT) return;
    const float* row = data + (size_t)b * NSITES;
    float left0 = 1.0f, left1 = 0.0f, left2 = 0.0f, left3 = 0.0f;
    float acc_nat = 0.0f, acc_l2 = 0.0f;
    for (int n = 0; n < NSITES; ++n) {
        STEP(row[n] == 1.0f, tensors + (size_t)n * 32);
    }
    out[b] = acc_nat - 0.6931471805599453f * acc_l2;
}

extern "C" void kernel_launch(void* const* d_in, const int* in_sizes, int n_in,
                              void* d_out, int out_size, void* d_ws, size_t ws_size,
                              hipStream_t stream) {
    const float* data    = (const float*)d_in[0];   // (16384, 784) float32
    const float* tensors = (const float*)d_in[1];   // (784, 4, 4, 2) float32
    float* out = (float*)d_out;                     // (16384,) float32

    // workspace layout (bytes)
    const size_t packed_bytes = (size_t)13 * BS_TOT * 8;                 //  1,703,936
    const size_t Pbuf_bytes   = (size_t)K_SEG * 16 * BS_TOT * 4;         // 16,777,216
    const size_t prefix_bytes = (size_t)K_SEG * 4 * BS_TOT * 4;          //  4,194,304
    const size_t res_bytes    = (size_t)K_SEG * BS_TOT * 4;              //  1,048,576
    const size_t need = packed_bytes + Pbuf_bytes + prefix_bytes + res_bytes;

    if (ws_size < need) {
        hipLaunchKernelGGL(amps_chain_kernel, dim3(BS_TOT / 64), dim3(64), 0, stream,
                           data, tensors, out);
        return;
    }

    char* wsb = (char*)d_ws;
    unsigned long long* packed = (unsigned long long*)wsb;
    float* Pbuf   = (float*)(wsb + packed_bytes);
    float* prefix = (float*)(wsb + packed_bytes + Pbuf_bytes);
    float* res    = (float*)(wsb + packed_bytes + Pbuf_bytes + prefix_bytes);

    hipLaunchKernelGGL(pack_kernel,   dim3(BS_TOT / 4 / 64), dim3(256), 0, stream, data, packed);
    hipLaunchKernelGGL(phase1_kernel, dim3(BS_TOT / 256, K_SEG), dim3(256), 0, stream,
                       tensors, packed, Pbuf);
    hipLaunchKernelGGL(phase2_kernel, dim3(BS_TOT / 256), dim3(256), 0, stream, Pbuf, prefix);
    hipLaunchKernelGGL(phase3_kernel, dim3(BS_TOT / 256, K_SEG), dim3(256), 0, stream,
                       tensors, packed, prefix, res);
    hipLaunchKernelGGL(reduce_kernel, dim3(BS_TOT / 256), dim3(256), 0, stream, res, out);
}

// Round 3
// 71.024 us; speedup vs baseline: 2.5653x; 1.1229x over previous
//
#include <hip/hip_runtime.h>

#define NSITES 784
#define BS_TOT 16384
#define K_SEG 28
#define G_SEG 28   // K_SEG * G_SEG == NSITES

// ---------------- per-site step (verified round 0, derivation-checked) ----------------
// t_ points at site tensor (32 floats, layout [l][r][p], flat l*8+r*2+p).
// Computes both matvecs; logits are the r=0 components; acc_l2 accumulates log2 units.
#define STEP(sbit, TP) do {                                                          \
    const float* t_ = (TP);                                                          \
    float p00 = fmaf(left0, t_[0],  fmaf(left1, t_[8],  fmaf(left2, t_[16], left3 * t_[24]))); \
    float p01 = fmaf(left0, t_[1],  fmaf(left1, t_[9],  fmaf(left2, t_[17], left3 * t_[25]))); \
    float p10 = fmaf(left0, t_[2],  fmaf(left1, t_[10], fmaf(left2, t_[18], left3 * t_[26]))); \
    float p11 = fmaf(left0, t_[3],  fmaf(left1, t_[11], fmaf(left2, t_[19], left3 * t_[27]))); \
    float p20 = fmaf(left0, t_[4],  fmaf(left1, t_[12], fmaf(left2, t_[20], left3 * t_[28]))); \
    float p21 = fmaf(left0, t_[5],  fmaf(left1, t_[13], fmaf(left2, t_[21], left3 * t_[29]))); \
    float p30 = fmaf(left0, t_[6],  fmaf(left1, t_[14], fmaf(left2, t_[22], left3 * t_[30]))); \
    float p31 = fmaf(left0, t_[7],  fmaf(left1, t_[15], fmaf(left2, t_[23], left3 * t_[31]))); \
    bool s_ = (sbit);                                                                \
    float lg0 = p00, lg1 = p01;                                                      \
    float mx_ = fmaxf(lg0, lg1);                                                     \
    float ch_ = s_ ? lg0 : lg1;                                                      \
    acc_nat += (ch_ - mx_);                                                          \
    float ad_ = fabsf(lg0 - lg1);                                                    \
    acc_l2 += __builtin_amdgcn_logf(1.0f + __builtin_amdgcn_exp2f(-ad_ * 1.4426950408889634f)); \
    left0 = s_ ? p00 : p01;                                                          \
    left1 = s_ ? p10 : p11;                                                          \
    left2 = s_ ? p20 : p21;                                                          \
    left3 = s_ ? p30 : p31;                                                          \
} while (0)

// ================= kernel 1: pack data bits (coalesced + ballot) =================
// packed[w][b] : bit j of word w = (data[b][w*64+j] == 1.0f). One wave per row.
__global__ __launch_bounds__(256) void pack_kernel(const float* __restrict__ data,
                                                   unsigned long long* __restrict__ packed) {
    int gid  = blockIdx.x * 256 + threadIdx.x;
    int row  = gid >> 6;
    int lane = threadIdx.x & 63;
    const float* r = data + (size_t)row * NSITES;
    #pragma unroll
    for (int w = 0; w < 12; ++w) {
        unsigned long long m = __ballot(r[w * 64 + lane] == 1.0f);
        if (lane == 0) packed[(size_t)w * BS_TOT + row] = m;
    }
    float v = (lane < 16) ? r[768 + lane] : 0.0f;
    unsigned long long m = __ballot((lane < 16) && (v == 1.0f));
    if (lane == 0) packed[(size_t)12 * BS_TOT + row] = m;
}

// helper: 28-bit window of data bits starting at site n0 (n0 = k*G_SEG, so word n0>>6 <= 11)
__device__ __forceinline__ unsigned long long bit_window(
        const unsigned long long* __restrict__ packed, int n0, int b) {
    int a0 = n0 >> 6, s = n0 & 63;
    unsigned long long w0 = packed[(size_t)a0 * BS_TOT + b];
    unsigned long long w1 = packed[(size_t)(a0 + 1) * BS_TOT + b];
    return s ? ((w0 >> s) | (w1 << (64 - s))) : w0;
}

// ================= kernel 2: per-segment 4x4 matrix products =================
// P_k = M_{kG} * ... * M_{kG+G-1} (row-vector convention). Pbuf layout: [k][b][i*4+j]
__global__ __launch_bounds__(256) void phase1_kernel(const float* __restrict__ tensors,
                                                     const unsigned long long* __restrict__ packed,
                                                     float* __restrict__ Pbuf) {
    int b = blockIdx.x * 256 + threadIdx.x;
    int k = blockIdx.y;

    __shared__ __align__(16) float lt[G_SEG * 32];
    {
        const float4* src = (const float4*)(tensors + (size_t)k * G_SEG * 32);
        if (threadIdx.x < G_SEG * 8) ((float4*)lt)[threadIdx.x] = src[threadIdx.x];
    }
    __syncthreads();

    unsigned long long win = bit_window(packed, k * G_SEG, b);

    float P[4][4];
    {
        const float* t = &lt[(win & 1ull) ? 0 : 1];
        #pragma unroll
        for (int l = 0; l < 4; ++l)
            #pragma unroll
            for (int j = 0; j < 4; ++j)
                P[l][j] = t[l * 8 + j * 2];
    }
    #pragma unroll 3
    for (int i = 1; i < G_SEG; ++i) {
        const float* t = &lt[i * 32 + (((win >> i) & 1ull) ? 0 : 1)];
        float M[4][4];
        #pragma unroll
        for (int l = 0; l < 4; ++l)
            #pragma unroll
            for (int j = 0; j < 4; ++j)
                M[l][j] = t[l * 8 + j * 2];
        float Q[4][4];
        #pragma unroll
        for (int r = 0; r < 4; ++r)
            #pragma unroll
            for (int j = 0; j < 4; ++j)
                Q[r][j] = fmaf(P[r][0], M[0][j], fmaf(P[r][1], M[1][j],
                          fmaf(P[r][2], M[2][j], P[r][3] * M[3][j])));
        #pragma unroll
        for (int r = 0; r < 4; ++r)
            #pragma unroll
            for (int j = 0; j < 4; ++j)
                P[r][j] = Q[r][j];
    }
    float4* pb = (float4*)(Pbuf + ((size_t)k * BS_TOT + b) * 16);
    #pragma unroll
    for (int r = 0; r < 4; ++r)
        pb[r] = make_float4(P[r][0], P[r][1], P[r][2], P[r][3]);
}

// ================= kernel 3: serial scan over K segments per sample =================
// prefix[k][r][b] = (e0 * P_0 * ... * P_{k-1})[r]
__global__ __launch_bounds__(256) void phase2_kernel(const float* __restrict__ Pbuf,
                                                     float* __restrict__ prefix) {
    int b = blockIdx.x * 256 + threadIdx.x;
    float l0 = 1.0f, l1 = 0.0f, l2 = 0.0f, l3 = 0.0f;
    #pragma unroll 4
    for (int k = 0; k < K_SEG; ++k) {
        prefix[((size_t)k * 4 + 0) * BS_TOT + b] = l0;
        prefix[((size_t)k * 4 + 1) * BS_TOT + b] = l1;
        prefix[((size_t)k * 4 + 2) * BS_TOT + b] = l2;
        prefix[((size_t)k * 4 + 3) * BS_TOT + b] = l3;
        const float4* pb = (const float4*)(Pbuf + ((size_t)k * BS_TOT + b) * 16);
        float4 r0 = pb[0], r1 = pb[1], r2 = pb[2], r3 = pb[3];
        float n0 = fmaf(l0, r0.x, fmaf(l1, r1.x, fmaf(l2, r2.x, l3 * r3.x)));
        float n1 = fmaf(l0, r0.y, fmaf(l1, r1.y, fmaf(l2, r2.y, l3 * r3.y)));
        float n2 = fmaf(l0, r0.z, fmaf(l1, r1.z, fmaf(l2, r2.z, l3 * r3.z)));
        float n3 = fmaf(l0, r0.w, fmaf(l1, r1.w, fmaf(l2, r2.w, l3 * r3.w)));
        l0 = n0; l1 = n1; l2 = n2; l3 = n3;
    }
}

// ================= kernel 4: per-segment log-softmax walk =================
__global__ __launch_bounds__(256) void phase3_kernel(const float* __restrict__ tensors,
                                                     const unsigned long long* __restrict__ packed,
                                                     const float* __restrict__ prefix,
                                                     float* __restrict__ res) {
    int b = blockIdx.x * 256 + threadIdx.x;
    int k = blockIdx.y;

    __shared__ __align__(16) float lt[G_SEG * 32];
    {
        const float4* src = (const float4*)(tensors + (size_t)k * G_SEG * 32);
        if (threadIdx.x < G_SEG * 8) ((float4*)lt)[threadIdx.x] = src[threadIdx.x];
    }
    __syncthreads();

    float left0 = prefix[((size_t)k * 4 + 0) * BS_TOT + b];
    float left1 = prefix[((size_t)k * 4 + 1) * BS_TOT + b];
    float left2 = prefix[((size_t)k * 4 + 2) * BS_TOT + b];
    float left3 = prefix[((size_t)k * 4 + 3) * BS_TOT + b];
    float acc_nat = 0.0f, acc_l2 = 0.0f;

    unsigned long long win = bit_window(packed, k * G_SEG, b);
    #pragma unroll 4
    for (int i = 0; i < G_SEG; ++i) {
        STEP(((win >> i) & 1ull) != 0, &lt[i * 32]);
    }
    res[(size_t)k * BS_TOT + b] = acc_nat - 0.6931471805599453f * acc_l2;
}

// ================= kernel 5: reduce partials =================
__global__ __launch_bounds__(256) void reduce_kernel(const float* __restrict__ res,
                                                     float* __restrict__ out) {
    int b = blockIdx.x * 256 + threadIdx.x;
    float a = 0.0f;
    #pragma unroll
    for (int k = 0; k < K_SEG; ++k) a += res[(size_t)k * BS_TOT + b];
    out[b] = a;
}

// ================= round-0 fallback (single kernel, known-correct) =================
__global__ __launch_bounds__(64) void amps_chain_kernel(
    const float* __restrict__ data, const float* __restrict__ tensors,
    float* __restrict__ out)
{
    int b = blockIdx.x * blockDim.x + threadIdx.x;
    if (b >= BS_TOT) return;
    const float* row = data + (size_t)b * NSITES;
    float left0 = 1.0f, left1 = 0.0f, left2 = 0.0f, left3 = 0.0f;
    float acc_nat = 0.0f, acc_l2 = 0.0f;
    for (int n = 0; n < NSITES; ++n) {
        STEP(row[n] == 1.0f, tensors + (size_t)n * 32);
    }
    out[b] = acc_nat - 0.6931471805599453f * acc_l2;
}

extern "C" void kernel_launch(void* const* d_in, const int* in_sizes, int n_in,
                              void* d_out, int out_size, void* d_ws, size_t ws_size,
                              hipStream_t stream) {
    const float* data    = (const float*)d_in[0];   // (16384, 784) float32
    const float* tensors = (const float*)d_in[1];   // (784, 4, 4, 2) float32
    float* out = (float*)d_out;                     // (16384,) float32

    const size_t packed_bytes = (size_t)13 * BS_TOT * 8;                  //  1,703,936
    const size_t Pbuf_bytes   = (size_t)K_SEG * BS_TOT * 16 * 4;          // 29,360,128
    const size_t prefix_bytes = (size_t)K_SEG * 4 * BS_TOT * 4;           //  7,340,032
    const size_t res_bytes    = (size_t)K_SEG * BS_TOT * 4;               //  1,835,008
    const size_t need = packed_bytes + Pbuf_bytes + prefix_bytes + res_bytes;

    if (ws_size < need) {
        hipLaunchKernelGGL(amps_chain_kernel, dim3(BS_TOT / 64), dim3(64), 0, stream,
                           data, tensors, out);
        return;
    }

    char* wsb = (char*)d_ws;
    unsigned long long* packed = (unsigned long long*)wsb;
    float* Pbuf   = (float*)(wsb + packed_bytes);
    float* prefix = (float*)(wsb + packed_bytes + Pbuf_bytes);
    float* res    = (float*)(wsb + packed_bytes + Pbuf_bytes + prefix_bytes);

    hipLaunchKernelGGL(pack_kernel,   dim3((BS_TOT * 64) / 256), dim3(256), 0, stream,
                       data, packed);
    hipLaunchKernelGGL(phase1_kernel, dim3(BS_TOT / 256, K_SEG), dim3(256), 0, stream,
                       tensors, packed, Pbuf);
    hipLaunchKernelGGL(phase2_kernel, dim3(BS_TOT / 256), dim3(256), 0, stream, Pbuf, prefix);
    hipLaunchKernelGGL(phase3_kernel, dim3(BS_TOT / 256, K_SEG), dim3(256), 0, stream,
                       tensors, packed, prefix, res);
    hipLaunchKernelGGL(reduce_kernel, dim3(BS_TOT / 256), dim3(256), 0, stream, res, out);
}

// Round 4
// 64.878 us; speedup vs baseline: 2.8083x; 1.0947x over previous
//
#include <hip/hip_runtime.h>

#define NSITES 784
#define BS_TOT 16384
#define K_SEG 28
#define G_SEG 28   // K_SEG * G_SEG == NSITES

// ---------------- per-site step (verified round 0/2, derivation-checked) ----------------
// t_ points at site tensor (32 floats, layout [l][r][p], flat l*8+r*2+p).
// Wave-uniform t_ -> compiler emits scalar s_load through K$.
#define STEP(sbit, TP) do {                                                          \
    const float* t_ = (TP);                                                          \
    float p00 = fmaf(left0, t_[0],  fmaf(left1, t_[8],  fmaf(left2, t_[16], left3 * t_[24]))); \
    float p01 = fmaf(left0, t_[1],  fmaf(left1, t_[9],  fmaf(left2, t_[17], left3 * t_[25]))); \
    float p10 = fmaf(left0, t_[2],  fmaf(left1, t_[10], fmaf(left2, t_[18], left3 * t_[26]))); \
    float p11 = fmaf(left0, t_[3],  fmaf(left1, t_[11], fmaf(left2, t_[19], left3 * t_[27]))); \
    float p20 = fmaf(left0, t_[4],  fmaf(left1, t_[12], fmaf(left2, t_[20], left3 * t_[28]))); \
    float p21 = fmaf(left0, t_[5],  fmaf(left1, t_[13], fmaf(left2, t_[21], left3 * t_[29]))); \
    float p30 = fmaf(left0, t_[6],  fmaf(left1, t_[14], fmaf(left2, t_[22], left3 * t_[30]))); \
    float p31 = fmaf(left0, t_[7],  fmaf(left1, t_[15], fmaf(left2, t_[23], left3 * t_[31]))); \
    bool s_ = (sbit);                                                                \
    float lg0 = p00, lg1 = p01;                                                      \
    float mx_ = fmaxf(lg0, lg1);                                                     \
    float ch_ = s_ ? lg0 : lg1;                                                      \
    acc_nat += (ch_ - mx_);                                                          \
    float ad_ = fabsf(lg0 - lg1);                                                    \
    acc_l2 += __builtin_amdgcn_logf(1.0f + __builtin_amdgcn_exp2f(-ad_ * 1.4426950408889634f)); \
    left0 = s_ ? p00 : p01;                                                          \
    left1 = s_ ? p10 : p11;                                                          \
    left2 = s_ ? p20 : p21;                                                          \
    left3 = s_ ? p30 : p31;                                                          \
} while (0)

// Q_row = P_row * M  (rows of M in float4 m0..m3)
#define MM_ROW(Q, Pr) do {                                                           \
    Q.x = fmaf(Pr.x, m0.x, fmaf(Pr.y, m1.x, fmaf(Pr.z, m2.x, Pr.w * m3.x)));         \
    Q.y = fmaf(Pr.x, m0.y, fmaf(Pr.y, m1.y, fmaf(Pr.z, m2.y, Pr.w * m3.y)));         \
    Q.z = fmaf(Pr.x, m0.z, fmaf(Pr.y, m1.z, fmaf(Pr.z, m2.z, Pr.w * m3.z)));         \
    Q.w = fmaf(Pr.x, m0.w, fmaf(Pr.y, m1.w, fmaf(Pr.z, m2.w, Pr.w * m3.w)));         \
} while (0)

// ================= kernel 1: pack data bits (coalesced + ballot) =================
__global__ __launch_bounds__(256) void pack_kernel(const float* __restrict__ data,
                                                   unsigned long long* __restrict__ packed) {
    int gid  = blockIdx.x * 256 + threadIdx.x;
    int row  = gid >> 6;
    int lane = threadIdx.x & 63;
    const float* r = data + (size_t)row * NSITES;
    #pragma unroll
    for (int w = 0; w < 12; ++w) {
        unsigned long long m = __ballot(r[w * 64 + lane] == 1.0f);
        if (lane == 0) packed[(size_t)w * BS_TOT + row] = m;
    }
    float v = (lane < 16) ? r[768 + lane] : 0.0f;
    unsigned long long m = __ballot((lane < 16) && (v == 1.0f));
    if (lane == 0) packed[(size_t)12 * BS_TOT + row] = m;
}

// 28-bit window of data bits starting at site n0 (n0 <= 756 -> words 0..12)
__device__ __forceinline__ unsigned long long bit_window(
        const unsigned long long* __restrict__ packed, int n0, int b) {
    int a0 = n0 >> 6, s = n0 & 63;
    unsigned long long w0 = packed[(size_t)a0 * BS_TOT + b];
    unsigned long long w1 = packed[(size_t)(a0 + 1) * BS_TOT + b];
    return s ? ((w0 >> s) | (w1 << (64 - s))) : w0;
}

// ================= kernel 2: per-segment 4x4 matrix products =================
// LDS layout transposed to [site][phys][l][r]; selected matrix = 4x ds_read_b128.
// P_k = M_{kG} * ... * M_{kG+G-1} (row-vector convention). Pbuf: [k][b][r*4+j]
__global__ __launch_bounds__(256) void phase1_kernel(const float* __restrict__ tensors,
                                                     const unsigned long long* __restrict__ packed,
                                                     float* __restrict__ Pbuf) {
    int b = blockIdx.x * 256 + threadIdx.x;
    int k = blockIdx.y;

    __shared__ __align__(16) float lt[G_SEG * 32];   // [i][p][l][r]
    const float* g = tensors + (size_t)k * G_SEG * 32;   // [i][l][r][p]
    for (int e = threadIdx.x; e < G_SEG * 32; e += 256) {
        int i = e >> 5, rem = e & 31;
        int l = rem >> 3, r = (rem >> 1) & 3, p = rem & 1;
        lt[i * 32 + p * 16 + l * 4 + r] = g[e];
    }
    __syncthreads();

    unsigned long long win = bit_window(packed, k * G_SEG, b);

    // site 0: P = selected matrix (x==1 -> phys slot 0)
    const float4* ms = (const float4*)&lt[(win & 1ull) ? 0 : 16];
    float4 P0 = ms[0], P1 = ms[1], P2 = ms[2], P3 = ms[3];

    #pragma unroll 3
    for (int i = 1; i < G_SEG; ++i) {
        const float4* mi = (const float4*)&lt[i * 32 + (((win >> i) & 1ull) ? 0 : 16)];
        float4 m0 = mi[0], m1 = mi[1], m2 = mi[2], m3 = mi[3];
        float4 Q0, Q1, Q2, Q3;
        MM_ROW(Q0, P0); MM_ROW(Q1, P1); MM_ROW(Q2, P2); MM_ROW(Q3, P3);
        P0 = Q0; P1 = Q1; P2 = Q2; P3 = Q3;
    }

    float4* pb = (float4*)(Pbuf + ((size_t)k * BS_TOT + b) * 16);
    pb[0] = P0; pb[1] = P1; pb[2] = P2; pb[3] = P3;
}

// ================= kernel 3: serial scan over K segments per sample =================
// prefix[k][r][b] = (e0 * P_0 * ... * P_{k-1})[r]
__global__ __launch_bounds__(64) void phase2_kernel(const float* __restrict__ Pbuf,
                                                    float* __restrict__ prefix) {
    int b = blockIdx.x * 64 + threadIdx.x;
    float l0 = 1.0f, l1 = 0.0f, l2 = 0.0f, l3 = 0.0f;
    const float4* base = (const float4*)Pbuf + (size_t)b * 4;
    #pragma unroll
    for (int k = 0; k < K_SEG; ++k) {
        prefix[((size_t)k * 4 + 0) * BS_TOT + b] = l0;
        prefix[((size_t)k * 4 + 1) * BS_TOT + b] = l1;
        prefix[((size_t)k * 4 + 2) * BS_TOT + b] = l2;
        prefix[((size_t)k * 4 + 3) * BS_TOT + b] = l3;
        if (k == K_SEG - 1) break;
        const float4* pb = base + (size_t)k * BS_TOT * 4;
        float4 r0 = pb[0], r1 = pb[1], r2 = pb[2], r3 = pb[3];
        float n0 = fmaf(l0, r0.x, fmaf(l1, r1.x, fmaf(l2, r2.x, l3 * r3.x)));
        float n1 = fmaf(l0, r0.y, fmaf(l1, r1.y, fmaf(l2, r2.y, l3 * r3.y)));
        float n2 = fmaf(l0, r0.z, fmaf(l1, r1.z, fmaf(l2, r2.z, l3 * r3.z)));
        float n3 = fmaf(l0, r0.w, fmaf(l1, r1.w, fmaf(l2, r2.w, l3 * r3.w)));
        l0 = n0; l1 = n1; l2 = n2; l3 = n3;
    }
}

// ================= kernel 4: per-segment log-softmax walk (scalar tensor loads) ==========
__global__ __launch_bounds__(256) void phase3_kernel(const float* __restrict__ tensors,
                                                     const unsigned long long* __restrict__ packed,
                                                     const float* __restrict__ prefix,
                                                     float* __restrict__ res) {
    int b = blockIdx.x * 256 + threadIdx.x;
    int k = blockIdx.y;
    const float* tb = tensors + (size_t)k * G_SEG * 32;

    float left0 = prefix[((size_t)k * 4 + 0) * BS_TOT + b];
    float left1 = prefix[((size_t)k * 4 + 1) * BS_TOT + b];
    float left2 = prefix[((size_t)k * 4 + 2) * BS_TOT + b];
    float left3 = prefix[((size_t)k * 4 + 3) * BS_TOT + b];
    float acc_nat = 0.0f, acc_l2 = 0.0f;

    unsigned long long win = bit_window(packed, k * G_SEG, b);
    #pragma unroll 4
    for (int i = 0; i < G_SEG; ++i) {
        STEP(((win >> i) & 1ull) != 0, tb + i * 32);
    }
    res[(size_t)k * BS_TOT + b] = acc_nat - 0.6931471805599453f * acc_l2;
}

// ================= kernel 5: reduce partials =================
__global__ __launch_bounds__(256) void reduce_kernel(const float* __restrict__ res,
                                                     float* __restrict__ out) {
    int b = blockIdx.x * 256 + threadIdx.x;
    float a = 0.0f;
    #pragma unroll
    for (int k = 0; k < K_SEG; ++k) a += res[(size_t)k * BS_TOT + b];
    out[b] = a;
}

// ================= round-0 fallback (single kernel, known-correct) =================
__global__ __launch_bounds__(64) void amps_chain_kernel(
    const float* __restrict__ data, const float* __restrict__ tensors,
    float* __restrict__ out)
{
    int b = blockIdx.x * blockDim.x + threadIdx.x;
    if (b >= BS_TOT) return;
    const float* row = data + (size_t)b * NSITES;
    float left0 = 1.0f, left1 = 0.0f, left2 = 0.0f, left3 = 0.0f;
    float acc_nat = 0.0f, acc_l2 = 0.0f;
    for (int n = 0; n < NSITES; ++n) {
        STEP(row[n] == 1.0f, tensors + (size_t)n * 32);
    }
    out[b] = acc_nat - 0.6931471805599453f * acc_l2;
}

extern "C" void kernel_launch(void* const* d_in, const int* in_sizes, int n_in,
                              void* d_out, int out_size, void* d_ws, size_t ws_size,
                              hipStream_t stream) {
    const float* data    = (const float*)d_in[0];   // (16384, 784) float32
    const float* tensors = (const float*)d_in[1];   // (784, 4, 4, 2) float32
    float* out = (float*)d_out;                     // (16384,) float32

    const size_t packed_bytes = (size_t)13 * BS_TOT * 8;                  //  1,703,936
    const size_t Pbuf_bytes   = (size_t)K_SEG * BS_TOT * 16 * 4;          // 29,360,128
    const size_t prefix_bytes = (size_t)K_SEG * 4 * BS_TOT * 4;           //  7,340,032
    const size_t res_bytes    = (size_t)K_SEG * BS_TOT * 4;               //  1,835,008
    const size_t need = packed_bytes + Pbuf_bytes + prefix_bytes + res_bytes;

    if (ws_size < need) {
        hipLaunchKernelGGL(amps_chain_kernel, dim3(BS_TOT / 64), dim3(64), 0, stream,
                           data, tensors, out);
        return;
    }

    char* wsb = (char*)d_ws;
    unsigned long long* packed = (unsigned long long*)wsb;
    float* Pbuf   = (float*)(wsb + packed_bytes);
    float* prefix = (float*)(wsb + packed_bytes + Pbuf_bytes);
    float* res    = (float*)(wsb + packed_bytes + Pbuf_bytes + prefix_bytes);

    hipLaunchKernelGGL(pack_kernel,   dim3((BS_TOT * 64) / 256), dim3(256), 0, stream,
                       data, packed);
    // last segment's product is never used by the prefix scan -> K_SEG-1 segments
    hipLaunchKernelGGL(phase1_kernel, dim3(BS_TOT / 256, K_SEG - 1), dim3(256), 0, stream,
                       tensors, packed, Pbuf);
    hipLaunchKernelGGL(phase2_kernel, dim3(BS_TOT / 64), dim3(64), 0, stream, Pbuf, prefix);
    hipLaunchKernelGGL(phase3_kernel, dim3(BS_TOT / 256, K_SEG), dim3(256), 0, stream,
                       tensors, packed, prefix, res);
    hipLaunchKernelGGL(reduce_kernel, dim3(BS_TOT / 256), dim3(256), 0, stream, res, out);
}